// Round 1
// baseline (1298.869 us; speedup 1.0000x reference)
//
#include <hip/hip_runtime.h>
#include <cstdint>

#define DIMSZ 1024
#define NH 16
#define HDIM 64
#define TLEN 4096
#define BSZ 4
#define EPSF 1.1920928955078125e-07f

typedef __bf16 bf16x8 __attribute__((ext_vector_type(8)));
typedef float f32x4 __attribute__((ext_vector_type(4)));
typedef uint16_t u16x8 __attribute__((ext_vector_type(8)));

__device__ __forceinline__ uint16_t f2bf(float f) {
  uint32_t u = __builtin_bit_cast(uint32_t, f);
  u += 0x7FFFu + ((u >> 16) & 1u);
  return (uint16_t)(u >> 16);
}
__device__ __forceinline__ float bf2f(uint16_t b) {
  return __builtin_bit_cast(float, ((uint32_t)b) << 16);
}

// async global->LDS, 16B per lane; LDS dest = wave-uniform base + lane*16
__device__ __forceinline__ void gl_lds16(const uint16_t* g, uint16_t* l) {
  __builtin_amdgcn_global_load_lds(
      (__attribute__((address_space(1))) uint32_t*)(g),
      (__attribute__((address_space(3))) uint32_t*)(l), 16, 0, 0);
}

// ---------------- fp32 -> bf16 cast (8 elems/thread) ----------------
__global__ __launch_bounds__(256) void cvt_f32_bf16(const float* __restrict__ src,
                                                    uint16_t* __restrict__ dst, int n8) {
  int i = blockIdx.x * 256 + threadIdx.x;
  if (i >= n8) return;
  const float4* s4 = ((const float4*)src) + (size_t)i * 2;
  float4 a = s4[0], b = s4[1];
  u16x8 o;
  o[0] = f2bf(a.x); o[1] = f2bf(a.y); o[2] = f2bf(a.z); o[3] = f2bf(a.w);
  o[4] = f2bf(b.x); o[5] = f2bf(b.y); o[6] = f2bf(b.z); o[7] = f2bf(b.w);
  *(((u16x8*)dst) + i) = o;
}

// ---------------- bf16 GEMM, C = A * W^T  (both row-major [.][K]) ----------------
// EPI=0: C fp32 [M][N].  EPI=1: scatter bf16 into q/k/v [B][H][T][64] layouts.
template <int EPI>
__global__ __launch_bounds__(256) void gemm_bt(const uint16_t* __restrict__ A,
                                               const uint16_t* __restrict__ Bw,
                                               float* __restrict__ C,
                                               uint16_t* __restrict__ q_out,
                                               uint16_t* __restrict__ k_out,
                                               uint16_t* __restrict__ v_out,
                                               int M, int N, int K) {
  __shared__ uint16_t As[128 * 32];
  __shared__ uint16_t Bs[128 * 32];
  const int nb = blockIdx.x, mb = blockIdx.y;
  const int tid = threadIdx.x;
  const int wave = tid >> 6, lane = tid & 63;
  const int l15 = lane & 15, l4 = lane >> 4;
  const int wr = wave >> 1, wc = wave & 1;

  f32x4 acc[4][4];
  const f32x4 fz = {0.f, 0.f, 0.f, 0.f};
#pragma unroll
  for (int i = 0; i < 4; ++i)
#pragma unroll
    for (int j = 0; j < 4; ++j) acc[i][j] = fz;

  const uint16_t* Ab = A + (size_t)mb * 128 * K;
  const uint16_t* Bb = Bw + (size_t)nb * 128 * K;
  const int rA = wave * 32 + (lane >> 2);
  const int cA = (lane & 3) * 8;

  for (int k0 = 0; k0 < K; k0 += 32) {
    gl_lds16(Ab + (size_t)rA * K + k0 + cA, &As[(wave * 32) * 32]);
    gl_lds16(Ab + (size_t)(rA + 16) * K + k0 + cA, &As[(wave * 32 + 16) * 32]);
    gl_lds16(Bb + (size_t)rA * K + k0 + cA, &Bs[(wave * 32) * 32]);
    gl_lds16(Bb + (size_t)(rA + 16) * K + k0 + cA, &Bs[(wave * 32 + 16) * 32]);
    __syncthreads();
    bf16x8 af[4], bfr[4];
#pragma unroll
    for (int i = 0; i < 4; ++i)
      af[i] = *(const bf16x8*)&As[(wr * 64 + i * 16 + l15) * 32 + l4 * 8];
#pragma unroll
    for (int j = 0; j < 4; ++j)
      bfr[j] = *(const bf16x8*)&Bs[(wc * 64 + j * 16 + l15) * 32 + l4 * 8];
#pragma unroll
    for (int i = 0; i < 4; ++i)
#pragma unroll
      for (int j = 0; j < 4; ++j)
        acc[i][j] = __builtin_amdgcn_mfma_f32_16x16x32_bf16(af[i], bfr[j], acc[i][j], 0, 0, 0);
    __syncthreads();
  }

  const int mrow = mb * 128 + wr * 64;
  const int ncol = nb * 128 + wc * 64;
  if (EPI == 0) {
#pragma unroll
    for (int i = 0; i < 4; ++i)
#pragma unroll
      for (int j = 0; j < 4; ++j) {
        int n = ncol + j * 16 + l15;
#pragma unroll
        for (int r = 0; r < 4; ++r) {
          int m = mrow + i * 16 + l4 * 4 + r;
          C[(size_t)m * N + n] = acc[i][j][r];
        }
      }
  } else {
#pragma unroll
    for (int i = 0; i < 4; ++i)
#pragma unroll
      for (int j = 0; j < 4; ++j) {
        int n = ncol + j * 16 + l15;
        int tens = n >> 10;
        int h = (n >> 6) & (NH - 1);
        int d = n & (HDIM - 1);
        uint16_t* dst = (tens == 0) ? q_out : ((tens == 1) ? k_out : v_out);
#pragma unroll
        for (int r = 0; r < 4; ++r) {
          int m = mrow + i * 16 + l4 * 4 + r;
          int b = m >> 12, t = m & (TLEN - 1);
          dst[((((size_t)b * NH + h) * TLEN) + t) * HDIM + d] = f2bf(acc[i][j][r]);
        }
      }
  }
}

// ---------------- RoPE + RMS-norm, in place on q/k [B][H][T][64] ----------------
// one wave per (b,h,t) row; q additionally scaled by 1/sqrt(HD)=0.125
__global__ __launch_bounds__(256) void rope_rms(uint16_t* __restrict__ qh,
                                                uint16_t* __restrict__ kh,
                                                const float* __restrict__ cosb,
                                                const float* __restrict__ sinb) {
  const int wid = blockIdx.x * 4 + (threadIdx.x >> 6);
  const int lane = threadIdx.x & 63;
  const int t = wid & (TLEN - 1);
  const int p = lane & 31;
  const float c = cosb[t * 32 + p];
  const float s = sinb[t * 32 + p];
  const size_t base = (size_t)wid * HDIM;
  {
    float v = bf2f(qh[base + lane]);
    float x1 = __shfl(v, p);
    float x2 = __shfl(v, p + 32);
    float rot = (lane < 32) ? (x1 * c + x2 * s) : (x2 * c - x1 * s);
    float ss = rot * rot;
#pragma unroll
    for (int off = 1; off < 64; off <<= 1) ss += __shfl_xor(ss, off);
    float sc = rsqrtf(ss * (1.0f / HDIM) + EPSF) * 0.125f;
    qh[base + lane] = f2bf(rot * sc);
  }
  {
    float v = bf2f(kh[base + lane]);
    float x1 = __shfl(v, p);
    float x2 = __shfl(v, p + 32);
    float rot = (lane < 32) ? (x1 * c + x2 * s) : (x2 * c - x1 * s);
    float ss = rot * rot;
#pragma unroll
    for (int off = 1; off < 64; off <<= 1) ss += __shfl_xor(ss, off);
    kh[base + lane] = f2bf(rot * rsqrtf(ss * (1.0f / HDIM) + EPSF));
  }
}

// ---------------- flash attention fwd ----------------
// block = one (b,h) x 64 q-rows; 4 waves x 16 rows; KV tiles of 64.
__global__ __launch_bounds__(256) void flash_attn(const uint16_t* __restrict__ qh,
                                                  const uint16_t* __restrict__ kh,
                                                  const uint16_t* __restrict__ vh,
                                                  uint16_t* __restrict__ yw) {
  __shared__ uint16_t Ks[64][72];       // K tile, row-major, +8 pad
  __shared__ uint16_t Vs[64][72];       // V tile TRANSPOSED: Vs[d][kv]
  __shared__ uint16_t Ps[4][16][72];    // per-wave P tile, padded
  const int bid = blockIdx.x;
  const int qt = bid & (TLEN / 64 - 1);
  const int bh = bid >> 6;  // b*NH + h
  const int tid = threadIdx.x;
  const int wave = tid >> 6, lane = tid & 63;
  const int l15 = lane & 15, l4 = lane >> 4;

  const uint16_t* qb = qh + ((size_t)bh * TLEN + qt * 64 + wave * 16) * HDIM;
  bf16x8 qf[2];
  qf[0] = *(const bf16x8*)(qb + l15 * HDIM + l4 * 8);
  qf[1] = *(const bf16x8*)(qb + l15 * HDIM + 32 + l4 * 8);

  const uint16_t* kb = kh + (size_t)bh * TLEN * HDIM;
  const uint16_t* vb = vh + (size_t)bh * TLEN * HDIM;

  f32x4 acc[4];
  const f32x4 fz = {0.f, 0.f, 0.f, 0.f};
#pragma unroll
  for (int j = 0; j < 4; ++j) acc[j] = fz;
  float m_r[4] = {-INFINITY, -INFINITY, -INFINITY, -INFINITY};
  float l_r[4] = {0.f, 0.f, 0.f, 0.f};

  for (int kv0 = 0; kv0 < TLEN; kv0 += 64) {
    __syncthreads();  // prev tile fully consumed
    // stage K (coalesced rows)
#pragma unroll
    for (int it = 0; it < 2; ++it) {
      int idx = tid + it * 256;
      int row = idx >> 3, c8 = (idx & 7) * 8;
      *(u16x8*)&Ks[row][c8] = *(const u16x8*)(kb + (size_t)(kv0 + row) * HDIM + c8);
    }
    // stage V transposed: Vs[d][kv]
#pragma unroll
    for (int it = 0; it < 2; ++it) {
      int idx = tid + it * 256;
      int row = idx & 63, c8 = (idx >> 6) * 8;
      u16x8 vv = *(const u16x8*)(vb + (size_t)(kv0 + row) * HDIM + c8);
#pragma unroll
      for (int e = 0; e < 8; ++e) Vs[c8 + e][row] = vv[e];
    }
    __syncthreads();

    // S = Q K^T (per wave: 16 q-rows x 64 kv-cols)
    f32x4 s[4];
#pragma unroll
    for (int j = 0; j < 4; ++j) s[j] = fz;
#pragma unroll
    for (int ks = 0; ks < 2; ++ks)
#pragma unroll
      for (int j = 0; j < 4; ++j) {
        bf16x8 kf = *(const bf16x8*)&Ks[j * 16 + l15][ks * 32 + l4 * 8];
        s[j] = __builtin_amdgcn_mfma_f32_16x16x32_bf16(qf[ks], kf, s[j], 0, 0, 0);
      }

    // online softmax (rows live in the 16-lane group sharing l4)
    float corr[4];
#pragma unroll
    for (int r = 0; r < 4; ++r) {
      float v = fmaxf(fmaxf(s[0][r], s[1][r]), fmaxf(s[2][r], s[3][r]));
#pragma unroll
      for (int off = 1; off < 16; off <<= 1) v = fmaxf(v, __shfl_xor(v, off));
      float mn = fmaxf(m_r[r], v);
      corr[r] = __expf(m_r[r] - mn);
      m_r[r] = mn;
    }
    float p[4][4];
#pragma unroll
    for (int j = 0; j < 4; ++j)
#pragma unroll
      for (int r = 0; r < 4; ++r) p[j][r] = __expf(s[j][r] - m_r[r]);
#pragma unroll
    for (int r = 0; r < 4; ++r) {
      float v = p[0][r] + p[1][r] + p[2][r] + p[3][r];
#pragma unroll
      for (int off = 1; off < 16; off <<= 1) v += __shfl_xor(v, off);
      l_r[r] = l_r[r] * corr[r] + v;
    }
#pragma unroll
    for (int j = 0; j < 4; ++j) {
      f32x4 tv = acc[j];
#pragma unroll
      for (int r = 0; r < 4; ++r) tv[r] *= corr[r];
      acc[j] = tv;
    }
    // P -> LDS (transpose to A-fragment layout)
#pragma unroll
    for (int j = 0; j < 4; ++j)
#pragma unroll
      for (int r = 0; r < 4; ++r) Ps[wave][l4 * 4 + r][j * 16 + l15] = f2bf(p[j][r]);
    __syncthreads();
    // O += P V
#pragma unroll
    for (int ks = 0; ks < 2; ++ks) {
      bf16x8 pf = *(const bf16x8*)&Ps[wave][l15][ks * 32 + l4 * 8];
#pragma unroll
      for (int j = 0; j < 4; ++j) {
        bf16x8 vf = *(const bf16x8*)&Vs[j * 16 + l15][ks * 32 + l4 * 8];
        acc[j] = __builtin_amdgcn_mfma_f32_16x16x32_bf16(pf, vf, acc[j], 0, 0, 0);
      }
    }
  }

  // epilogue: y[b][t][h*64+d] = acc / l
  const int trow = qt * 64 + wave * 16;
  const int b = bh >> 4, h = bh & (NH - 1);
#pragma unroll
  for (int j = 0; j < 4; ++j) {
    int d = j * 16 + l15;
#pragma unroll
    for (int r = 0; r < 4; ++r) {
      int t = trow + l4 * 4 + r;
      float val = acc[j][r] / l_r[r];
      yw[((size_t)b * TLEN + t) * DIMSZ + h * HDIM + d] = f2bf(val);
    }
  }
}

// ---------------- launch ----------------
extern "C" void kernel_launch(void* const* d_in, const int* in_sizes, int n_in,
                              void* d_out, int out_size, void* d_ws, size_t ws_size,
                              hipStream_t stream) {
  const float* x = (const float*)d_in[0];
  const float* cosb = (const float*)d_in[1];
  const float* sinb = (const float*)d_in[2];
  const float* wq = (const float*)d_in[3];
  const float* wk = (const float*)d_in[4];
  const float* wv = (const float*)d_in[5];
  const float* wo = (const float*)d_in[6];
  float* out = (float*)d_out;

  char* w = (char*)d_ws;
  uint16_t* qh = (uint16_t*)w;    w += (size_t)BSZ * NH * TLEN * HDIM * 2;  // 32 MB
  uint16_t* kh = (uint16_t*)w;    w += (size_t)BSZ * NH * TLEN * HDIM * 2;  // 32 MB
  uint16_t* vh = (uint16_t*)w;    w += (size_t)BSZ * NH * TLEN * HDIM * 2;  // 32 MB
  uint16_t* xb = (uint16_t*)w;    w += (size_t)BSZ * TLEN * DIMSZ * 2;      // 32 MB (reused as y)
  uint16_t* wqkvb = (uint16_t*)w; w += (size_t)3 * DIMSZ * DIMSZ * 2;       // 6 MB
  uint16_t* wob = (uint16_t*)w;   w += (size_t)DIMSZ * DIMSZ * 2;           // 2 MB

  // casts to bf16
  cvt_f32_bf16<<<8192, 256, 0, stream>>>(x, xb, 2097152);
  cvt_f32_bf16<<<512, 256, 0, stream>>>(wq, wqkvb, 131072);
  cvt_f32_bf16<<<512, 256, 0, stream>>>(wk, wqkvb + DIMSZ * DIMSZ, 131072);
  cvt_f32_bf16<<<512, 256, 0, stream>>>(wv, wqkvb + 2 * DIMSZ * DIMSZ, 131072);
  cvt_f32_bf16<<<512, 256, 0, stream>>>(wo, wob, 131072);

  // fused QKV projection -> per-head layouts
  gemm_bt<1><<<dim3(24, 128), 256, 0, stream>>>(xb, wqkvb, nullptr, qh, kh, vh,
                                                BSZ * TLEN, 3 * DIMSZ, DIMSZ);
  // rope + rms-norm in place (q scaled by 0.125)
  rope_rms<<<65536, 256, 0, stream>>>(qh, kh, cosb, sinb);
  // attention -> y (bf16, [B][T][H*64]) into xb's space
  flash_attn<<<4096, 256, 0, stream>>>(qh, kh, vh, xb);
  // output projection -> fp32 d_out
  gemm_bt<0><<<dim3(8, 128), 256, 0, stream>>>(xb, wob, out, nullptr, nullptr, nullptr,
                                               BSZ * TLEN, DIMSZ, DIMSZ);
}

// Round 2
// 1236.752 us; speedup vs baseline: 1.0502x; 1.0502x over previous
//
#include <hip/hip_runtime.h>
#include <cstdint>

#define DIMSZ 1024
#define NH 16
#define HDIM 64
#define TLEN 4096
#define BSZ 4
#define EPSF 1.1920928955078125e-07f

typedef __bf16 bf16x8 __attribute__((ext_vector_type(8)));
typedef float f32x4 __attribute__((ext_vector_type(4)));
typedef uint16_t u16x8 __attribute__((ext_vector_type(8)));

__device__ __forceinline__ uint16_t f2bf(float f) {
  uint32_t u = __builtin_bit_cast(uint32_t, f);
  u += 0x7FFFu + ((u >> 16) & 1u);
  return (uint16_t)(u >> 16);
}
__device__ __forceinline__ float bf2f(uint16_t b) {
  return __builtin_bit_cast(float, ((uint32_t)b) << 16);
}

// async global->LDS, 16B per lane; LDS dest = wave-uniform base + lane*16
__device__ __forceinline__ void gl_lds16(const uint16_t* g, uint16_t* l) {
  __builtin_amdgcn_global_load_lds(
      (__attribute__((address_space(1))) uint32_t*)(g),
      (__attribute__((address_space(3))) uint32_t*)(l), 16, 0, 0);
}

// ---------------- fp32 -> bf16 cast (8 elems/thread) ----------------
__global__ __launch_bounds__(256) void cvt_f32_bf16(const float* __restrict__ src,
                                                    uint16_t* __restrict__ dst, int n8) {
  int i = blockIdx.x * 256 + threadIdx.x;
  if (i >= n8) return;
  const float4* s4 = ((const float4*)src) + (size_t)i * 2;
  float4 a = s4[0], b = s4[1];
  u16x8 o;
  o[0] = f2bf(a.x); o[1] = f2bf(a.y); o[2] = f2bf(a.z); o[3] = f2bf(a.w);
  o[4] = f2bf(b.x); o[5] = f2bf(b.y); o[6] = f2bf(b.z); o[7] = f2bf(b.w);
  *(((u16x8*)dst) + i) = o;
}

// ---------------- bf16 GEMM, C = A * W^T  (both row-major [.][K]) ----------------
// EPI=0: C fp32 [M][N].  EPI=1: scatter bf16 into q/k/v [B][H][T][64] layouts.
template <int EPI>
__global__ __launch_bounds__(256) void gemm_bt(const uint16_t* __restrict__ A,
                                               const uint16_t* __restrict__ Bw,
                                               float* __restrict__ C,
                                               uint16_t* __restrict__ q_out,
                                               uint16_t* __restrict__ k_out,
                                               uint16_t* __restrict__ v_out,
                                               int M, int N, int K) {
  __shared__ uint16_t As[128 * 32];
  __shared__ uint16_t Bs[128 * 32];
  const int nb = blockIdx.x, mb = blockIdx.y;
  const int tid = threadIdx.x;
  const int wave = tid >> 6, lane = tid & 63;
  const int l15 = lane & 15, l4 = lane >> 4;
  const int wr = wave >> 1, wc = wave & 1;

  f32x4 acc[4][4];
  const f32x4 fz = {0.f, 0.f, 0.f, 0.f};
#pragma unroll
  for (int i = 0; i < 4; ++i)
#pragma unroll
    for (int j = 0; j < 4; ++j) acc[i][j] = fz;

  const uint16_t* Ab = A + (size_t)mb * 128 * K;
  const uint16_t* Bb = Bw + (size_t)nb * 128 * K;
  const int rA = wave * 32 + (lane >> 2);
  const int cA = (lane & 3) * 8;

  for (int k0 = 0; k0 < K; k0 += 32) {
    gl_lds16(Ab + (size_t)rA * K + k0 + cA, &As[(wave * 32) * 32]);
    gl_lds16(Ab + (size_t)(rA + 16) * K + k0 + cA, &As[(wave * 32 + 16) * 32]);
    gl_lds16(Bb + (size_t)rA * K + k0 + cA, &Bs[(wave * 32) * 32]);
    gl_lds16(Bb + (size_t)(rA + 16) * K + k0 + cA, &Bs[(wave * 32 + 16) * 32]);
    __syncthreads();
    bf16x8 af[4], bfr[4];
#pragma unroll
    for (int i = 0; i < 4; ++i)
      af[i] = *(const bf16x8*)&As[(wr * 64 + i * 16 + l15) * 32 + l4 * 8];
#pragma unroll
    for (int j = 0; j < 4; ++j)
      bfr[j] = *(const bf16x8*)&Bs[(wc * 64 + j * 16 + l15) * 32 + l4 * 8];
#pragma unroll
    for (int i = 0; i < 4; ++i)
#pragma unroll
      for (int j = 0; j < 4; ++j)
        acc[i][j] = __builtin_amdgcn_mfma_f32_16x16x32_bf16(af[i], bfr[j], acc[i][j], 0, 0, 0);
    __syncthreads();
  }

  const int mrow = mb * 128 + wr * 64;
  const int ncol = nb * 128 + wc * 64;
  if (EPI == 0) {
#pragma unroll
    for (int i = 0; i < 4; ++i)
#pragma unroll
      for (int j = 0; j < 4; ++j) {
        int n = ncol + j * 16 + l15;
#pragma unroll
        for (int r = 0; r < 4; ++r) {
          int m = mrow + i * 16 + l4 * 4 + r;
          C[(size_t)m * N + n] = acc[i][j][r];
        }
      }
  } else {
#pragma unroll
    for (int i = 0; i < 4; ++i)
#pragma unroll
      for (int j = 0; j < 4; ++j) {
        int n = ncol + j * 16 + l15;
        int tens = n >> 10;
        int h = (n >> 6) & (NH - 1);
        int d = n & (HDIM - 1);
        uint16_t* dst = (tens == 0) ? q_out : ((tens == 1) ? k_out : v_out);
#pragma unroll
        for (int r = 0; r < 4; ++r) {
          int m = mrow + i * 16 + l4 * 4 + r;
          int b = m >> 12, t = m & (TLEN - 1);
          dst[((((size_t)b * NH + h) * TLEN) + t) * HDIM + d] = f2bf(acc[i][j][r]);
        }
      }
  }
}

// ---------------- RoPE + RMS-norm, in place on q/k [B][H][T][64] ----------------
__global__ __launch_bounds__(256) void rope_rms(uint16_t* __restrict__ qh,
                                                uint16_t* __restrict__ kh,
                                                const float* __restrict__ cosb,
                                                const float* __restrict__ sinb) {
  const int wid = blockIdx.x * 4 + (threadIdx.x >> 6);
  const int lane = threadIdx.x & 63;
  const int t = wid & (TLEN - 1);
  const int p = lane & 31;
  const float c = cosb[t * 32 + p];
  const float s = sinb[t * 32 + p];
  const size_t base = (size_t)wid * HDIM;
  {
    float v = bf2f(qh[base + lane]);
    float x1 = __shfl(v, p);
    float x2 = __shfl(v, p + 32);
    float rot = (lane < 32) ? (x1 * c + x2 * s) : (x2 * c - x1 * s);
    float ss = rot * rot;
#pragma unroll
    for (int off = 1; off < 64; off <<= 1) ss += __shfl_xor(ss, off);
    float sc = rsqrtf(ss * (1.0f / HDIM) + EPSF) * 0.125f;
    qh[base + lane] = f2bf(rot * sc);
  }
  {
    float v = bf2f(kh[base + lane]);
    float x1 = __shfl(v, p);
    float x2 = __shfl(v, p + 32);
    float rot = (lane < 32) ? (x1 * c + x2 * s) : (x2 * c - x1 * s);
    float ss = rot * rot;
#pragma unroll
    for (int off = 1; off < 64; off <<= 1) ss += __shfl_xor(ss, off);
    kh[base + lane] = f2bf(rot * rsqrtf(ss * (1.0f / HDIM) + EPSF));
  }
}

// ---------------- flash attention fwd ----------------
// block = one (b,h) x 128 q-rows; 4 waves x 32 rows; KV tiles of 64.
// K staged via global_load_lds with XOR-swizzled source; V staged transposed;
// P per-wave LDS (no barrier); defer-max online softmax.
__global__ __launch_bounds__(256) void flash_attn(const uint16_t* __restrict__ qh,
                                                  const uint16_t* __restrict__ kh,
                                                  const uint16_t* __restrict__ vh,
                                                  uint16_t* __restrict__ yw) {
  __shared__ uint16_t Ksm[64 * 64];    // K tile, rows linear, 16B chunks XOR-swizzled
  __shared__ uint16_t Vs[64][72];      // V tile TRANSPOSED: Vs[d][kv], +8 pad
  __shared__ uint16_t Ps[4][32][72];   // per-wave P tile, padded
  const int braw = blockIdx.x;
  const int bid = (braw & 7) * 256 + (braw >> 3);  // XCD swizzle (2048 % 8 == 0)
  const int qt = bid & 31;      // 32 q-tiles of 128
  const int bh = bid >> 5;      // b*NH + h
  const int tid = threadIdx.x;
  const int wave = tid >> 6, lane = tid & 63;
  const int l15 = lane & 15, l4 = lane >> 4;

  // Q fragments: 32 rows per wave, 2 frags of 16 rows x K=64
  const uint16_t* qb = qh + ((size_t)bh * TLEN + qt * 128 + wave * 32) * HDIM;
  bf16x8 qf[2][2];
#pragma unroll
  for (int qi = 0; qi < 2; ++qi)
#pragma unroll
    for (int kk = 0; kk < 2; ++kk)
      qf[qi][kk] = *(const bf16x8*)(qb + (qi * 16 + l15) * HDIM + kk * 32 + l4 * 8);

  const uint16_t* kb = kh + (size_t)bh * TLEN * HDIM;
  const uint16_t* vb = vh + (size_t)bh * TLEN * HDIM;

  // K staging: wave stages rows [wave*16, wave*16+16), src chunk pre-swizzled
  const int krow = wave * 16 + (lane >> 3);
  const int kc8 = (lane & 7) ^ (krow & 7);
  const size_t koff = (size_t)krow * HDIM + kc8 * 8;
  uint16_t* ks_dst = &Ksm[wave * 16 * 64];

  f32x4 acc[2][4];
  const f32x4 fz = {0.f, 0.f, 0.f, 0.f};
#pragma unroll
  for (int qi = 0; qi < 2; ++qi)
#pragma unroll
    for (int j = 0; j < 4; ++j) acc[qi][j] = fz;
  float m_r[2][4], l_r[2][4];
#pragma unroll
  for (int qi = 0; qi < 2; ++qi)
#pragma unroll
    for (int r = 0; r < 4; ++r) { m_r[qi][r] = -INFINITY; l_r[qi][r] = 0.f; }

  for (int kv0 = 0; kv0 < TLEN; kv0 += 64) {
    __syncthreads();  // prev tile fully consumed
    // K: async global->LDS (swizzled src, linear dest)
    gl_lds16(kb + (size_t)kv0 * HDIM + koff, ks_dst);
    gl_lds16(kb + (size_t)kv0 * HDIM + koff + 8 * HDIM, ks_dst + 8 * 64);
    // V transposed: Vs[d][kv]
#pragma unroll
    for (int it = 0; it < 2; ++it) {
      int idx = tid + it * 256;
      int row = idx & 63, c8 = (idx >> 6) * 8;
      u16x8 vv = *(const u16x8*)(vb + (size_t)(kv0 + row) * HDIM + c8);
#pragma unroll
      for (int e = 0; e < 8; ++e) Vs[c8 + e][row] = vv[e];
    }
    __syncthreads();

    // S = Q K^T : per wave 32 q-rows x 64 kv
    f32x4 s[2][4];
#pragma unroll
    for (int qi = 0; qi < 2; ++qi)
#pragma unroll
      for (int j = 0; j < 4; ++j) s[qi][j] = fz;
#pragma unroll
    for (int kk = 0; kk < 2; ++kk)
#pragma unroll
      for (int j = 0; j < 4; ++j) {
        int row = j * 16 + l15;
        int col = (kk * 32 + l4 * 8) ^ ((row & 7) * 8);
        bf16x8 kf = *(const bf16x8*)&Ksm[row * 64 + col];
        s[0][j] = __builtin_amdgcn_mfma_f32_16x16x32_bf16(qf[0][kk], kf, s[0][j], 0, 0, 0);
        s[1][j] = __builtin_amdgcn_mfma_f32_16x16x32_bf16(qf[1][kk], kf, s[1][j], 0, 0, 0);
      }

    // online softmax with defer-max (rows live across the 16 lanes sharing l4)
    float pmax[2][4];
    int need = 0;
#pragma unroll
    for (int qi = 0; qi < 2; ++qi)
#pragma unroll
      for (int r = 0; r < 4; ++r) {
        float v = fmaxf(fmaxf(s[qi][0][r], s[qi][1][r]), fmaxf(s[qi][2][r], s[qi][3][r]));
#pragma unroll
        for (int off = 1; off < 16; off <<= 1) v = fmaxf(v, __shfl_xor(v, off));
        pmax[qi][r] = v;
        need |= (v > m_r[qi][r] + 8.0f) ? 1 : 0;
      }
    if (__any(need)) {
#pragma unroll
      for (int qi = 0; qi < 2; ++qi)
#pragma unroll
        for (int r = 0; r < 4; ++r) {
          float mn = fmaxf(m_r[qi][r], pmax[qi][r]);
          float c = __expf(m_r[qi][r] - mn);
          m_r[qi][r] = mn;
          l_r[qi][r] *= c;
#pragma unroll
          for (int j = 0; j < 4; ++j) acc[qi][j][r] *= c;
        }
    }
#pragma unroll
    for (int qi = 0; qi < 2; ++qi)
#pragma unroll
      for (int j = 0; j < 4; ++j)
#pragma unroll
        for (int r = 0; r < 4; ++r) s[qi][j][r] = __expf(s[qi][j][r] - m_r[qi][r]);
#pragma unroll
    for (int qi = 0; qi < 2; ++qi)
#pragma unroll
      for (int r = 0; r < 4; ++r) {
        float v = s[qi][0][r] + s[qi][1][r] + s[qi][2][r] + s[qi][3][r];
#pragma unroll
        for (int off = 1; off < 16; off <<= 1) v += __shfl_xor(v, off);
        l_r[qi][r] += v;
      }
    // P -> per-wave LDS (no barrier needed; same-wave dep)
#pragma unroll
    for (int qi = 0; qi < 2; ++qi)
#pragma unroll
      for (int j = 0; j < 4; ++j)
#pragma unroll
        for (int r = 0; r < 4; ++r)
          Ps[wave][qi * 16 + l4 * 4 + r][j * 16 + l15] = f2bf(s[qi][j][r]);

    // O += P V
#pragma unroll
    for (int kk = 0; kk < 2; ++kk) {
      bf16x8 pf0 = *(const bf16x8*)&Ps[wave][l15][kk * 32 + l4 * 8];
      bf16x8 pf1 = *(const bf16x8*)&Ps[wave][16 + l15][kk * 32 + l4 * 8];
#pragma unroll
      for (int j = 0; j < 4; ++j) {
        bf16x8 vf = *(const bf16x8*)&Vs[j * 16 + l15][kk * 32 + l4 * 8];
        acc[0][j] = __builtin_amdgcn_mfma_f32_16x16x32_bf16(pf0, vf, acc[0][j], 0, 0, 0);
        acc[1][j] = __builtin_amdgcn_mfma_f32_16x16x32_bf16(pf1, vf, acc[1][j], 0, 0, 0);
      }
    }
  }

  // epilogue: y[b][t][h*64+d] = acc / l
  const int trow = qt * 128 + wave * 32;
  const int b = bh >> 4, h = bh & (NH - 1);
#pragma unroll
  for (int qi = 0; qi < 2; ++qi)
#pragma unroll
    for (int j = 0; j < 4; ++j) {
      int d = j * 16 + l15;
#pragma unroll
      for (int r = 0; r < 4; ++r) {
        int t = trow + qi * 16 + l4 * 4 + r;
        float val = acc[qi][j][r] / l_r[qi][r];
        yw[((size_t)b * TLEN + t) * DIMSZ + h * HDIM + d] = f2bf(val);
      }
    }
}

// ---------------- launch ----------------
extern "C" void kernel_launch(void* const* d_in, const int* in_sizes, int n_in,
                              void* d_out, int out_size, void* d_ws, size_t ws_size,
                              hipStream_t stream) {
  const float* x = (const float*)d_in[0];
  const float* cosb = (const float*)d_in[1];
  const float* sinb = (const float*)d_in[2];
  const float* wq = (const float*)d_in[3];
  const float* wk = (const float*)d_in[4];
  const float* wv = (const float*)d_in[5];
  const float* wo = (const float*)d_in[6];
  float* out = (float*)d_out;

  char* w = (char*)d_ws;
  uint16_t* qh = (uint16_t*)w;    w += (size_t)BSZ * NH * TLEN * HDIM * 2;  // 32 MB
  uint16_t* kh = (uint16_t*)w;    w += (size_t)BSZ * NH * TLEN * HDIM * 2;  // 32 MB
  uint16_t* vh = (uint16_t*)w;    w += (size_t)BSZ * NH * TLEN * HDIM * 2;  // 32 MB
  uint16_t* xb = (uint16_t*)w;    w += (size_t)BSZ * TLEN * DIMSZ * 2;      // 32 MB (reused as y)
  uint16_t* wqkvb = (uint16_t*)w; w += (size_t)3 * DIMSZ * DIMSZ * 2;       // 6 MB
  uint16_t* wob = (uint16_t*)w;   w += (size_t)DIMSZ * DIMSZ * 2;           // 2 MB

  // casts to bf16
  cvt_f32_bf16<<<8192, 256, 0, stream>>>(x, xb, 2097152);
  cvt_f32_bf16<<<512, 256, 0, stream>>>(wq, wqkvb, 131072);
  cvt_f32_bf16<<<512, 256, 0, stream>>>(wk, wqkvb + DIMSZ * DIMSZ, 131072);
  cvt_f32_bf16<<<512, 256, 0, stream>>>(wv, wqkvb + 2 * DIMSZ * DIMSZ, 131072);
  cvt_f32_bf16<<<512, 256, 0, stream>>>(wo, wob, 131072);

  // fused QKV projection -> per-head layouts
  gemm_bt<1><<<dim3(24, 128), 256, 0, stream>>>(xb, wqkvb, nullptr, qh, kh, vh,
                                                BSZ * TLEN, 3 * DIMSZ, DIMSZ);
  // rope + rms-norm in place (q scaled by 0.125)
  rope_rms<<<65536, 256, 0, stream>>>(qh, kh, cosb, sinb);
  // attention -> y (bf16, [B][T][H*64]) into xb's space
  flash_attn<<<2048, 256, 0, stream>>>(qh, kh, vh, xb);
  // output projection -> fp32 d_out
  gemm_bt<0><<<dim3(8, 128), 256, 0, stream>>>(xb, wob, out, nullptr, nullptr, nullptr,
                                               BSZ * TLEN, DIMSZ, DIMSZ);
}

// Round 4
// 799.235 us; speedup vs baseline: 1.6251x; 1.5474x over previous
//
#include <hip/hip_runtime.h>
#include <cstdint>

#define DIMSZ 1024
#define NH 16
#define HDIM 64
#define TLEN 4096
#define BSZ 4
#define EPSF 1.1920928955078125e-07f

typedef __bf16 bf16x8 __attribute__((ext_vector_type(8)));
typedef float f32x4 __attribute__((ext_vector_type(4)));
typedef float f32x16 __attribute__((ext_vector_type(16)));
typedef uint16_t u16x8 __attribute__((ext_vector_type(8)));

__device__ __forceinline__ uint16_t f2bf(float f) {
  uint32_t u = __builtin_bit_cast(uint32_t, f);
  u += 0x7FFFu + ((u >> 16) & 1u);
  return (uint16_t)(u >> 16);
}
__device__ __forceinline__ float bf2f(uint16_t b) {
  return __builtin_bit_cast(float, ((uint32_t)b) << 16);
}

// async global->LDS, 16B per lane; LDS dest = wave-uniform base + lane*16
__device__ __forceinline__ void gl_lds16(const uint16_t* g, uint16_t* l) {
  __builtin_amdgcn_global_load_lds(
      (__attribute__((address_space(1))) uint32_t*)(g),
      (__attribute__((address_space(3))) uint32_t*)(l), 16, 0, 0);
}

// pack two f32 -> two bf16 in one u32 (low = a, high = b), HW RTNE
__device__ __forceinline__ uint32_t cvtpk(float a, float b) {
  uint32_t r;
  asm volatile("v_cvt_pk_bf16_f32 %0, %1, %2" : "=v"(r) : "v"(a), "v"(b));
  return r;
}
// swap upper-32-lanes of a with lower-32-lanes of b (both updated).
// NOTE: operands must hold DISTINCT values (distinct live registers).
__device__ __forceinline__ void pls32(uint32_t& a, uint32_t& b) {
  asm volatile("v_permlane32_swap_b32 %0, %1" : "+v"(a), "+v"(b));
}
// cross-half pair reductions via shfl (safe: compiler-generated)
__device__ __forceinline__ float pairmax32(float x) {
  return fmaxf(x, __shfl_xor(x, 32));
}
__device__ __forceinline__ float pairsum32(float x) {
  return x + __shfl_xor(x, 32);
}

// ---------------- fp32 -> bf16 cast (8 elems/thread) ----------------
__global__ __launch_bounds__(256) void cvt_f32_bf16(const float* __restrict__ src,
                                                    uint16_t* __restrict__ dst, int n8) {
  int i = blockIdx.x * 256 + threadIdx.x;
  if (i >= n8) return;
  const float4* s4 = ((const float4*)src) + (size_t)i * 2;
  float4 a = s4[0], b = s4[1];
  u16x8 o;
  o[0] = f2bf(a.x); o[1] = f2bf(a.y); o[2] = f2bf(a.z); o[3] = f2bf(a.w);
  o[4] = f2bf(b.x); o[5] = f2bf(b.y); o[6] = f2bf(b.z); o[7] = f2bf(b.w);
  *(((u16x8*)dst) + i) = o;
}

// ---------------- bf16 GEMM, C = A * W^T  (both row-major [.][K]) ----------------
template <int EPI>
__global__ __launch_bounds__(256) void gemm_bt(const uint16_t* __restrict__ A,
                                               const uint16_t* __restrict__ Bw,
                                               float* __restrict__ C,
                                               uint16_t* __restrict__ q_out,
                                               uint16_t* __restrict__ k_out,
                                               uint16_t* __restrict__ v_out,
                                               int M, int N, int K) {
  __shared__ uint16_t As[128 * 32];
  __shared__ uint16_t Bs[128 * 32];
  const int nb = blockIdx.x, mb = blockIdx.y;
  const int tid = threadIdx.x;
  const int wave = tid >> 6, lane = tid & 63;
  const int l15 = lane & 15, l4 = lane >> 4;
  const int wr = wave >> 1, wc = wave & 1;

  f32x4 acc[4][4];
  const f32x4 fz = {0.f, 0.f, 0.f, 0.f};
#pragma unroll
  for (int i = 0; i < 4; ++i)
#pragma unroll
    for (int j = 0; j < 4; ++j) acc[i][j] = fz;

  const uint16_t* Ab = A + (size_t)mb * 128 * K;
  const uint16_t* Bb = Bw + (size_t)nb * 128 * K;
  const int rA = wave * 32 + (lane >> 2);
  const int cA = (lane & 3) * 8;

  for (int k0 = 0; k0 < K; k0 += 32) {
    gl_lds16(Ab + (size_t)rA * K + k0 + cA, &As[(wave * 32) * 32]);
    gl_lds16(Ab + (size_t)(rA + 16) * K + k0 + cA, &As[(wave * 32 + 16) * 32]);
    gl_lds16(Bb + (size_t)rA * K + k0 + cA, &Bs[(wave * 32) * 32]);
    gl_lds16(Bb + (size_t)(rA + 16) * K + k0 + cA, &Bs[(wave * 32 + 16) * 32]);
    __syncthreads();
    bf16x8 af[4], bfr[4];
#pragma unroll
    for (int i = 0; i < 4; ++i)
      af[i] = *(const bf16x8*)&As[(wr * 64 + i * 16 + l15) * 32 + l4 * 8];
#pragma unroll
    for (int j = 0; j < 4; ++j)
      bfr[j] = *(const bf16x8*)&Bs[(wc * 64 + j * 16 + l15) * 32 + l4 * 8];
#pragma unroll
    for (int i = 0; i < 4; ++i)
#pragma unroll
      for (int j = 0; j < 4; ++j)
        acc[i][j] = __builtin_amdgcn_mfma_f32_16x16x32_bf16(af[i], bfr[j], acc[i][j], 0, 0, 0);
    __syncthreads();
  }

  const int mrow = mb * 128 + wr * 64;
  const int ncol = nb * 128 + wc * 64;
  if (EPI == 0) {
#pragma unroll
    for (int i = 0; i < 4; ++i)
#pragma unroll
      for (int j = 0; j < 4; ++j) {
        int n = ncol + j * 16 + l15;
#pragma unroll
        for (int r = 0; r < 4; ++r) {
          int m = mrow + i * 16 + l4 * 4 + r;
          C[(size_t)m * N + n] = acc[i][j][r];
        }
      }
  } else {
#pragma unroll
    for (int i = 0; i < 4; ++i)
#pragma unroll
      for (int j = 0; j < 4; ++j) {
        int n = ncol + j * 16 + l15;
        int tens = n >> 10;
        int h = (n >> 6) & (NH - 1);
        int d = n & (HDIM - 1);
        uint16_t* dst = (tens == 0) ? q_out : ((tens == 1) ? k_out : v_out);
#pragma unroll
        for (int r = 0; r < 4; ++r) {
          int m = mrow + i * 16 + l4 * 4 + r;
          int b = m >> 12, t = m & (TLEN - 1);
          dst[((((size_t)b * NH + h) * TLEN) + t) * HDIM + d] = f2bf(acc[i][j][r]);
        }
      }
  }
}

// ---------------- RoPE + RMS-norm, in place on q/k [B][H][T][64] ----------------
__global__ __launch_bounds__(256) void rope_rms(uint16_t* __restrict__ qh,
                                                uint16_t* __restrict__ kh,
                                                const float* __restrict__ cosb,
                                                const float* __restrict__ sinb) {
  const int wid = blockIdx.x * 4 + (threadIdx.x >> 6);
  const int lane = threadIdx.x & 63;
  const int t = wid & (TLEN - 1);
  const int p = lane & 31;
  const float c = cosb[t * 32 + p];
  const float s = sinb[t * 32 + p];
  const size_t base = (size_t)wid * HDIM;
  {
    float v = bf2f(qh[base + lane]);
    float x1 = __shfl(v, p);
    float x2 = __shfl(v, p + 32);
    float rot = (lane < 32) ? (x1 * c + x2 * s) : (x2 * c - x1 * s);
    float ss = rot * rot;
#pragma unroll
    for (int off = 1; off < 64; off <<= 1) ss += __shfl_xor(ss, off);
    float sc = rsqrtf(ss * (1.0f / HDIM) + EPSF) * 0.125f;
    qh[base + lane] = f2bf(rot * sc);
  }
  {
    float v = bf2f(kh[base + lane]);
    float x1 = __shfl(v, p);
    float x2 = __shfl(v, p + 32);
    float rot = (lane < 32) ? (x1 * c + x2 * s) : (x2 * c - x1 * s);
    float ss = rot * rot;
#pragma unroll
    for (int off = 1; off < 64; off <<= 1) ss += __shfl_xor(ss, off);
    kh[base + lane] = f2bf(rot * rsqrtf(ss * (1.0f / HDIM) + EPSF));
  }
}

// ---------------- flash attention fwd (swapped QK^T, in-register softmax) ----------
// block = one (b,h) x 128 q-rows; 4 waves x 32 rows; KV tiles of 64; 32x32x16 MFMA.
// S^T = K*Q^T -> each lane owns one q-column's scores in registers.
// PV: O^T = V^T * P^T ; P fragments built via cvt_pk + permlane32_swap (T12).
__global__ __launch_bounds__(256) void flash_attn(const uint16_t* __restrict__ qh,
                                                  const uint16_t* __restrict__ kh,
                                                  const uint16_t* __restrict__ vh,
                                                  uint16_t* __restrict__ yw) {
  __shared__ __align__(16) char smem_raw[18432];
  uint16_t* Ksm = (uint16_t*)smem_raw;            // [64][64] linear, chunks XOR-swizzled
  uint16_t* Vsm = (uint16_t*)(smem_raw + 8192);   // [64][72] transposed: Vsm[d][kv]

  const int braw = blockIdx.x;
  const int bid = (braw & 7) * 256 + (braw >> 3);  // XCD swizzle (2048 % 8 == 0)
  const int qt = bid & 31;      // 32 q-tiles of 128
  const int bh = bid >> 5;      // b*NH + h
  const int tid = threadIdx.x;
  const int wave = tid >> 6, lane = tid & 63;
  const int q5 = lane & 31, hi = lane >> 5;

  // Q^T B-fragments in registers: lane holds Q[q5][ks*16 + hi*8 + 0..7]
  const uint16_t* qb = qh + ((size_t)bh * TLEN + qt * 128 + wave * 32) * HDIM;
  bf16x8 qf[4];
#pragma unroll
  for (int ks = 0; ks < 4; ++ks)
    qf[ks] = *(const bf16x8*)(qb + q5 * HDIM + ks * 16 + hi * 8);

  const uint16_t* kb = kh + (size_t)bh * TLEN * HDIM;
  const uint16_t* vb = vh + (size_t)bh * TLEN * HDIM;

  // K staging: wave stages rows [wave*16, +16), src chunk pre-swizzled
  const int krow = wave * 16 + (lane >> 3);
  const int kc8 = (lane & 7) ^ (krow & 7);
  const size_t koff = (size_t)krow * HDIM + kc8 * 8;
  uint16_t* ks_dst = &Ksm[wave * 16 * 64];

  f32x16 accO[2];
  float m_run = -INFINITY, l_run = 0.f;
#pragma unroll
  for (int db = 0; db < 2; ++db)
#pragma unroll
    for (int r = 0; r < 16; ++r) accO[db][r] = 0.f;

  for (int kv0 = 0; kv0 < TLEN; kv0 += 64) {
    __syncthreads();  // prev tile fully consumed
    gl_lds16(kb + (size_t)kv0 * HDIM + koff, ks_dst);
    gl_lds16(kb + (size_t)kv0 * HDIM + koff + 8 * HDIM, ks_dst + 8 * 64);
    // V transposed: Vsm[d][kv]
#pragma unroll
    for (int it = 0; it < 2; ++it) {
      int idx = tid + it * 256;
      int row = idx & 63, c8 = (idx >> 6) * 8;
      u16x8 vv = *(const u16x8*)(vb + (size_t)(kv0 + row) * HDIM + c8);
#pragma unroll
      for (int e = 0; e < 8; ++e) Vsm[(c8 + e) * 72 + row] = vv[e];
    }
    __syncthreads();

    // S^T = K Q^T : sA = kv rows 0..31, sB = kv rows 32..63; col(lane&31) = q
    f32x16 sA, sB;
#pragma unroll
    for (int r = 0; r < 16; ++r) { sA[r] = 0.f; sB[r] = 0.f; }
#pragma unroll
    for (int ks = 0; ks < 4; ++ks) {
      int cc = ((ks * 2 + hi) ^ (q5 & 7)) * 8;
      bf16x8 kf0 = *(const bf16x8*)&Ksm[q5 * 64 + cc];
      bf16x8 kf1 = *(const bf16x8*)&Ksm[(32 + q5) * 64 + cc];
      sA = __builtin_amdgcn_mfma_f32_32x32x16_bf16(kf0, qf[ks], sA, 0, 0, 0);
      sB = __builtin_amdgcn_mfma_f32_32x32x16_bf16(kf1, qf[ks], sB, 0, 0, 0);
    }

    // in-register online softmax for this lane's q-column
    float pm = sA[0];
#pragma unroll
    for (int r = 1; r < 16; ++r) pm = fmaxf(pm, sA[r]);
#pragma unroll
    for (int r = 0; r < 16; ++r) pm = fmaxf(pm, sB[r]);
    pm = pairmax32(pm);
    if (__any(pm > m_run + 8.0f)) {  // defer-max (T13)
      float mn = fmaxf(m_run, pm);
      float c = __expf(m_run - mn);
      m_run = mn;
      l_run *= c;
#pragma unroll
      for (int db = 0; db < 2; ++db)
#pragma unroll
        for (int r = 0; r < 16; ++r) accO[db][r] *= c;
    }
#pragma unroll
    for (int r = 0; r < 16; ++r) {
      sA[r] = __expf(sA[r] - m_run);
      sB[r] = __expf(sB[r] - m_run);
    }
    float sm = 0.f;
#pragma unroll
    for (int r = 0; r < 16; ++r) sm += sA[r] + sB[r];
    l_run += pairsum32(sm);

    // P^T B-fragments: pack to bf16, redistribute halves via permlane32_swap
    bf16x8 pf[4];
    {
      uint32_t a0, a1, b0, b1;
      a0 = cvtpk(sA[0], sA[1]);  a1 = cvtpk(sA[2], sA[3]);
      b0 = cvtpk(sA[4], sA[5]);  b1 = cvtpk(sA[6], sA[7]);
      pls32(a0, b0); pls32(a1, b1);
      uint4 u = make_uint4(a0, a1, b0, b1);
      pf[0] = __builtin_bit_cast(bf16x8, u);
      a0 = cvtpk(sA[8], sA[9]);  a1 = cvtpk(sA[10], sA[11]);
      b0 = cvtpk(sA[12], sA[13]); b1 = cvtpk(sA[14], sA[15]);
      pls32(a0, b0); pls32(a1, b1);
      u = make_uint4(a0, a1, b0, b1);
      pf[1] = __builtin_bit_cast(bf16x8, u);
      a0 = cvtpk(sB[0], sB[1]);  a1 = cvtpk(sB[2], sB[3]);
      b0 = cvtpk(sB[4], sB[5]);  b1 = cvtpk(sB[6], sB[7]);
      pls32(a0, b0); pls32(a1, b1);
      u = make_uint4(a0, a1, b0, b1);
      pf[2] = __builtin_bit_cast(bf16x8, u);
      a0 = cvtpk(sB[8], sB[9]);  a1 = cvtpk(sB[10], sB[11]);
      b0 = cvtpk(sB[12], sB[13]); b1 = cvtpk(sB[14], sB[15]);
      pls32(a0, b0); pls32(a1, b1);
      u = make_uint4(a0, a1, b0, b1);
      pf[3] = __builtin_bit_cast(bf16x8, u);
    }

    // O^T += V^T P^T
#pragma unroll
    for (int ksl = 0; ksl < 4; ++ksl) {
#pragma unroll
      for (int db = 0; db < 2; ++db) {
        bf16x8 vf = *(const bf16x8*)&Vsm[(db * 32 + q5) * 72 + ksl * 16 + hi * 8];
        accO[db] = __builtin_amdgcn_mfma_f32_32x32x16_bf16(vf, pf[ksl], accO[db], 0, 0, 0);
      }
    }
  }

  // epilogue: transpose O^T through LDS, coalesced bf16 stores
  __syncthreads();  // all waves done with Ksm/Vsm
  uint16_t* Epi = (uint16_t*)smem_raw + wave * 2304;  // [32][72] per wave
  float inv = 1.0f / l_run;
#pragma unroll
  for (int db = 0; db < 2; ++db)
#pragma unroll
    for (int r = 0; r < 16; ++r) {
      int d = db * 32 + (r & 3) + 8 * (r >> 2) + 4 * hi;
      Epi[q5 * 72 + d] = f2bf(accO[db][r] * inv);
    }
  // same-wave ds_write -> ds_read: compiler inserts lgkmcnt wait
  const int b = bh >> 4, h = bh & (NH - 1);
#pragma unroll
  for (int i = 0; i < 4; ++i) {
    int c = lane + i * 64;
    int row = c >> 3, off = (c & 7) * 8;
    u16x8 vv = *(const u16x8*)&Epi[row * 72 + off];
    int t = qt * 128 + wave * 32 + row;
    *(u16x8*)&yw[((size_t)b * TLEN + t) * DIMSZ + h * HDIM + off] = vv;
  }
}

// ---------------- launch ----------------
extern "C" void kernel_launch(void* const* d_in, const int* in_sizes, int n_in,
                              void* d_out, int out_size, void* d_ws, size_t ws_size,
                              hipStream_t stream) {
  const float* x = (const float*)d_in[0];
  const float* cosb = (const float*)d_in[1];
  const float* sinb = (const float*)d_in[2];
  const float* wq = (const float*)d_in[3];
  const float* wk = (const float*)d_in[4];
  const float* wv = (const float*)d_in[5];
  const float* wo = (const float*)d_in[6];
  float* out = (float*)d_out;

  char* w = (char*)d_ws;
  uint16_t* qh = (uint16_t*)w;    w += (size_t)BSZ * NH * TLEN * HDIM * 2;  // 32 MB
  uint16_t* kh = (uint16_t*)w;    w += (size_t)BSZ * NH * TLEN * HDIM * 2;  // 32 MB
  uint16_t* vh = (uint16_t*)w;    w += (size_t)BSZ * NH * TLEN * HDIM * 2;  // 32 MB
  uint16_t* xb = (uint16_t*)w;    w += (size_t)BSZ * TLEN * DIMSZ * 2;      // 32 MB (reused as y)
  uint16_t* wqkvb = (uint16_t*)w; w += (size_t)3 * DIMSZ * DIMSZ * 2;       // 6 MB
  uint16_t* wob = (uint16_t*)w;   w += (size_t)DIMSZ * DIMSZ * 2;           // 2 MB

  // casts to bf16
  cvt_f32_bf16<<<8192, 256, 0, stream>>>(x, xb, 2097152);
  cvt_f32_bf16<<<512, 256, 0, stream>>>(wq, wqkvb, 131072);
  cvt_f32_bf16<<<512, 256, 0, stream>>>(wk, wqkvb + DIMSZ * DIMSZ, 131072);
  cvt_f32_bf16<<<512, 256, 0, stream>>>(wv, wqkvb + 2 * DIMSZ * DIMSZ, 131072);
  cvt_f32_bf16<<<512, 256, 0, stream>>>(wo, wob, 131072);

  // fused QKV projection -> per-head layouts
  gemm_bt<1><<<dim3(24, 128), 256, 0, stream>>>(xb, wqkvb, nullptr, qh, kh, vh,
                                                BSZ * TLEN, 3 * DIMSZ, DIMSZ);
  // rope + rms-norm in place (q scaled by 0.125)
  rope_rms<<<65536, 256, 0, stream>>>(qh, kh, cosb, sinb);
  // attention -> y (bf16, [B][T][H*64]) into xb's space
  flash_attn<<<2048, 256, 0, stream>>>(qh, kh, vh, xb);
  // output projection -> fp32 d_out
  gemm_bt<0><<<dim3(8, 128), 256, 0, stream>>>(xb, wob, out, nullptr, nullptr, nullptr,
                                               BSZ * TLEN, DIMSZ, DIMSZ);
}